// Round 8
// baseline (170.248 us; speedup 1.0000x reference)
//
#include <hip/hip_runtime.h>
#include <hip/hip_bf16.h>
#include <stdint.h>

#define N1 8192
#define N2 16384
#define DIM 256
#define BM 256              // rows per block = 4 waves x 64
#define CS 16               // col-splits
#define COLS (N2 / CS)      // 1024 cols per block
#define TC 32               // cols per tile (ct=2)
#define NT (COLS / TC)      // 32 tiles per block
#define NPART CS

typedef short v8s  __attribute__((ext_vector_type(8)));   // 8 x bf16 bits
typedef float f32x4 __attribute__((ext_vector_type(4)));

#define GLD16(g, l)                                                                         \
  __builtin_amdgcn_global_load_lds((const __attribute__((address_space(1))) uint32_t*)(g),  \
                                   (__attribute__((address_space(3))) uint32_t*)(l), 16, 0, 0)

__device__ __forceinline__ void top3_insert(float v, float& t0, float& t1, float& t2) {
    float nt1 = __builtin_amdgcn_fmed3f(v, t0, t1);
    float nt2 = __builtin_amdgcn_fmed3f(v, t1, t2);
    t0 = fmaxf(t0, v);
    t1 = nt1;
    t2 = nt2;
}

// 16 lanes per row, 4 rows per wave, 16 rows per block. Each lane: 4 x float4
// loads in flight (ILP), 4-step width-16 shuffle reduce, 4 x uint2 stores.
__global__ __launch_bounds__(256) void normalize_kernel(
        const float* __restrict__ inA, const float* __restrict__ inB,
        __hip_bfloat16* __restrict__ outA, __hip_bfloat16* __restrict__ outB) {
    const int wave = threadIdx.x >> 6;
    const int lane = threadIdx.x & 63;
    const int rgrp = lane >> 4;
    const int li   = lane & 15;
    const int gr   = blockIdx.x * 16 + wave * 4 + rgrp;   // 0..24575
    const float* in;
    __hip_bfloat16* out;
    int row;
    if (gr < N1) { in = inA; out = outA; row = gr; }
    else         { in = inB; out = outB; row = gr - N1; }
    const float* rp = in + (size_t)row * DIM + li * 4;
    float4 v[4];
    #pragma unroll
    for (int j = 0; j < 4; ++j) v[j] = *(const float4*)(rp + j * 64);
    float s = 0.f;
    #pragma unroll
    for (int j = 0; j < 4; ++j)
        s += v[j].x * v[j].x + v[j].y * v[j].y + v[j].z * v[j].z + v[j].w * v[j].w;
    #pragma unroll
    for (int off = 8; off; off >>= 1) s += __shfl_xor(s, off, 64);
    const float inv = 1.0f / sqrtf(s);
    __hip_bfloat16* wp = out + (size_t)row * DIM + li * 4;
    #pragma unroll
    for (int j = 0; j < 4; ++j) {
        __hip_bfloat16 o[4];
        o[0] = __float2bfloat16(v[j].x * inv);
        o[1] = __float2bfloat16(v[j].y * inv);
        o[2] = __float2bfloat16(v[j].z * inv);
        o[3] = __float2bfloat16(v[j].w * inv);
        *(uint2*)(wp + j * 64) = *(uint2*)o;
    }
}

// A-in-registers GEMM+top3, rt=4, 4-WAVE BLOCKS.
// R7 POST-MORTEM: with 8-wave blocks the compiler hard-capped VGPR at 128
// (counters bit-identical to R6: VGPR=128, 21.5MB scratch writes) and af
// spilled -> 108us at 25% MfmaUtil vs the 33us per-SIMD MFMA floor.
// Now: block = 4 waves x 64 rows = 256 rows x 1024 cols; grid 512 = 2
// blocks/CU. __launch_bounds__(256,2) yields a 256-VGPR cap under BOTH the
// waves-per-EU reading (512/2) and a blocks-per-CU reading (2*4/4=2/EU);
// amdgpu_waves_per_eu(2,2) states it explicitly. Demand ~235 < 256.
// Per CU steady state: LDS reads 2 blocks x 4 waves x 16 b128 = 1536 cyc/tile
// vs MFMA 2 waves/SIMD x 64 = 2483 cyc/tile -> matrix-pipe dominant; two
// independent blocks/CU overlap barrier drains (R0-proven mechanism).
// B streams through LDS: 16 KB tiles, double-buffered, staged 2 ahead,
// counted vmcnt(4) gates (never 0 until drain), 2 barriers/tile.
// cs = bid&15; bid%8 = cs%8 -> all 32 blocks of a cs land on one XCD (512 KB
// B slab L2-resident). Swizzle: col c chunk g at phys g^(c&7); conflicts
// measured negligible (~0.25 extra cyc/read).
__global__ __launch_bounds__(256, 2) __attribute__((amdgpu_waves_per_eu(2, 2)))
void gemm_top3_kernel(
        const __hip_bfloat16* __restrict__ A, const __hip_bfloat16* __restrict__ B,
        float* __restrict__ partial) {
    __shared__ char smem[2 * 16384];   // B tile double buffer

    const int tid  = threadIdx.x;
    const int wave = tid >> 6;
    const int lane = tid & 63;
    const int lo   = lane & 15;
    const int quad = lane >> 4;
    const int cs   = blockIdx.x & 15;  // bid%8 == cs%8 -> XCD-resident B slab
    const int rb   = blockIdx.x >> 4;
    const int row0 = rb * BM;

    // ---- A fragments in registers: af[rt][s] = A[row0+wave*64+rt*16+lo][s*32+quad*8 ..+7]
    v8s af[4][8];
    {
        const char* arow = (const char*)A + (size_t)(row0 + wave * 64 + lo) * 512 + quad * 16;
        #pragma unroll
        for (int rt = 0; rt < 4; ++rt)
            #pragma unroll
            for (int s = 0; s < 8; ++s)
                af[rt][s] = *(const v8s*)(arow + rt * 8192 + s * 64);
    }
    // af loads must complete before staging so in-loop vmcnt counts are pure B.
    asm volatile("s_waitcnt vmcnt(0)" ::: "memory");

    // ---- staging constants: 4 GLD16/thread/tile. For j=0..3:
    // col = j*8 + wave*2 + (lane>>5); phys chunk = lane&31;
    // source logical chunk = (lane&31)^(col&7). LDS dst = j*4096 + wave*1024
    // (+ lane*16 by HW) == col*512 + phys*16 exactly. ----
    const char* Bb = (const char*)B + (size_t)cs * COLS * 512;
    int gsrc[4];
    #pragma unroll
    for (int j = 0; j < 4; ++j) {
        const int col = j * 8 + wave * 2 + (lane >> 5);
        gsrc[j] = col * 512 + (((lane & 31) ^ (col & 7)) << 4);
    }

    // ---- read-side swizzle: phys = (s*4+quad) ^ (col&7); (16+lo)&7 == lo&7 ----
    int swz[8];
    #pragma unroll
    for (int s = 0; s < 8; ++s) swz[s] = (((s * 4 + quad) ^ (lo & 7)) << 4);
    const int bco0 = lo * 512;            // ct=0: col lo
    const int bco1 = (16 + lo) * 512;     // ct=1: col 16+lo

    float t0[16], t1[16], t2[16];
    #pragma unroll
    for (int i = 0; i < 16; ++i) { t0[i] = -1e30f; t1[i] = -1e30f; t2[i] = -1e30f; }

    // ---- prologue: stage tiles 0 and 1 ----
    #pragma unroll
    for (int j = 0; j < 4; ++j)
        GLD16(Bb + gsrc[j], smem + j * 4096 + wave * 1024);
    #pragma unroll
    for (int j = 0; j < 4; ++j)
        GLD16(Bb + 16384 + gsrc[j], smem + 16384 + j * 4096 + wave * 1024);

    #pragma unroll 2
    for (int t = 0; t < NT; ++t) {
        if (t == NT - 1) asm volatile("s_waitcnt vmcnt(0)" ::: "memory");
        else             asm volatile("s_waitcnt vmcnt(4)" ::: "memory");
        __builtin_amdgcn_s_barrier();    // all waves: tile t landed

        const char* bbuf = smem + (t & 1) * 16384;
        f32x4 acc[4][2];
        __builtin_amdgcn_s_setprio(1);
        #pragma unroll
        for (int s = 0; s < 8; ++s) {
            v8s bf0 = *(const v8s*)(bbuf + bco0 + swz[s]);
            v8s bf1 = *(const v8s*)(bbuf + bco1 + swz[s]);
            #pragma unroll
            for (int rt = 0; rt < 4; ++rt) {
                if (s == 0) {
                    acc[rt][0] = __builtin_amdgcn_mfma_f32_16x16x32_bf16(
                        af[rt][0], bf0, (f32x4){0.f, 0.f, 0.f, 0.f}, 0, 0, 0);
                    acc[rt][1] = __builtin_amdgcn_mfma_f32_16x16x32_bf16(
                        af[rt][0], bf1, (f32x4){0.f, 0.f, 0.f, 0.f}, 0, 0, 0);
                } else {
                    acc[rt][0] = __builtin_amdgcn_mfma_f32_16x16x32_bf16(
                        af[rt][s], bf0, acc[rt][0], 0, 0, 0);
                    acc[rt][1] = __builtin_amdgcn_mfma_f32_16x16x32_bf16(
                        af[rt][s], bf1, acc[rt][1], 0, 0, 0);
                }
            }
        }
        __builtin_amdgcn_s_setprio(0);
        __builtin_amdgcn_s_barrier();    // all waves done reading buf[t&1]
        if (t + 2 < NT) {                // stage t+2 into the buffer just freed
            const char* src = Bb + (size_t)(t + 2) * 16384;
            char* dst = smem + (t & 1) * 16384;
            #pragma unroll
            for (int j = 0; j < 4; ++j)
                GLD16(src + gsrc[j], dst + j * 4096 + wave * 1024);
        }
        // fold this tile's 32 C-values/lane into running top3 (VALU; hides
        // under the in-flight stage)
        #pragma unroll
        for (int rt = 0; rt < 4; ++rt)
            #pragma unroll
            for (int r = 0; r < 4; ++r) {
                const int sl = rt * 4 + r;
                top3_insert(acc[rt][0][r], t0[sl], t1[sl], t2[sl]);
                top3_insert(acc[rt][1][r], t0[sl], t1[sl], t2[sl]);
            }
    }

    // merge across the 16 lo-lanes (same row, different col residues)
    #pragma unroll
    for (int sl = 0; sl < 16; ++sl) {
        #pragma unroll
        for (int step = 1; step < 16; step <<= 1) {
            float b0 = __shfl_xor(t0[sl], step, 64);
            float b1 = __shfl_xor(t1[sl], step, 64);
            float b2 = __shfl_xor(t2[sl], step, 64);
            top3_insert(b0, t0[sl], t1[sl], t2[sl]);
            top3_insert(b1, t0[sl], t1[sl], t2[sl]);
            top3_insert(b2, t0[sl], t1[sl], t2[sl]);
        }
    }
    if (lo == 0) {
        #pragma unroll
        for (int rt = 0; rt < 4; ++rt)
            #pragma unroll
            for (int r = 0; r < 4; ++r) {
                const int row = row0 + wave * 64 + rt * 16 + quad * 4 + r;
                float* p = partial + ((size_t)row * NPART + cs) * 3;
                const int sl = rt * 4 + r;
                p[0] = t0[sl]; p[1] = t1[sl]; p[2] = t2[sl];
            }
    }
}

// 1 thread per row: 12 float4 loads (48 values), 48 inserts.
__global__ __launch_bounds__(256) void merge_kernel(
        const float* __restrict__ partial, float* __restrict__ out) {
    const int row = blockIdx.x * 256 + threadIdx.x;
    if (row >= N1) return;
    const float4* p = (const float4*)(partial + (size_t)row * NPART * 3);
    float t0 = -1e30f, t1 = -1e30f, t2 = -1e30f;
    #pragma unroll
    for (int i = 0; i < 12; ++i) {
        float4 v = p[i];
        top3_insert(v.x, t0, t1, t2);
        top3_insert(v.y, t0, t1, t2);
        top3_insert(v.z, t0, t1, t2);
        top3_insert(v.w, t0, t1, t2);
    }
    out[row] = (t0 + t1 + t2) * (1.0f / 3.0f);
}

extern "C" void kernel_launch(void* const* d_in, const int* in_sizes, int n_in,
                              void* d_out, int out_size, void* d_ws, size_t ws_size,
                              hipStream_t stream) {
    const float* tA = (const float*)d_in[0];
    const float* tB = (const float*)d_in[1];
    float* out = (float*)d_out;

    __hip_bfloat16* An = (__hip_bfloat16*)d_ws;
    __hip_bfloat16* Bn = An + (size_t)N1 * DIM;
    float* partial = (float*)(Bn + (size_t)N2 * DIM);

    normalize_kernel<<<(N1 + N2) / 16, 256, 0, stream>>>(tA, tB, An, Bn);
    gemm_top3_kernel<<<(N1 / BM) * CS, 256, 0, stream>>>(An, Bn, partial);
    merge_kernel<<<N1 / 256, 256, 0, stream>>>(partial, out);
}

// Round 9
// 145.722 us; speedup vs baseline: 1.1683x; 1.1683x over previous
//
#include <hip/hip_runtime.h>
#include <hip/hip_bf16.h>
#include <stdint.h>

#define N1 8192
#define N2 16384
#define DIM 256
#define BM 128              // rows per block = 4 waves x 32
#define CS 8                // col-splits (== 8 XCDs)
#define COLS (N2 / CS)      // 2048 cols per block
#define TC 64               // cols per tile (ct=4)
#define NT (COLS / TC)      // 32 tiles per block
#define NPART CS

typedef short v8s  __attribute__((ext_vector_type(8)));   // 8 x bf16 bits
typedef float f32x4 __attribute__((ext_vector_type(4)));

#define GLD16(g, l)                                                                         \
  __builtin_amdgcn_global_load_lds((const __attribute__((address_space(1))) uint32_t*)(g),  \
                                   (__attribute__((address_space(3))) uint32_t*)(l), 16, 0, 0)

__device__ __forceinline__ void top3_insert(float v, float& t0, float& t1, float& t2) {
    float nt1 = __builtin_amdgcn_fmed3f(v, t0, t1);
    float nt2 = __builtin_amdgcn_fmed3f(v, t1, t2);
    t0 = fmaxf(t0, v);
    t1 = nt1;
    t2 = nt2;
}

// 16 lanes per row, 4 rows per wave, 16 rows per block. Each lane: 4 x float4
// loads in flight (ILP), 4-step width-16 shuffle reduce, 4 x uint2 stores.
__global__ __launch_bounds__(256) void normalize_kernel(
        const float* __restrict__ inA, const float* __restrict__ inB,
        __hip_bfloat16* __restrict__ outA, __hip_bfloat16* __restrict__ outB) {
    const int wave = threadIdx.x >> 6;
    const int lane = threadIdx.x & 63;
    const int rgrp = lane >> 4;
    const int li   = lane & 15;
    const int gr   = blockIdx.x * 16 + wave * 4 + rgrp;   // 0..24575
    const float* in;
    __hip_bfloat16* out;
    int row;
    if (gr < N1) { in = inA; out = outA; row = gr; }
    else         { in = inB; out = outB; row = gr - N1; }
    const float* rp = in + (size_t)row * DIM + li * 4;
    float4 v[4];
    #pragma unroll
    for (int j = 0; j < 4; ++j) v[j] = *(const float4*)(rp + j * 64);
    float s = 0.f;
    #pragma unroll
    for (int j = 0; j < 4; ++j)
        s += v[j].x * v[j].x + v[j].y * v[j].y + v[j].z * v[j].z + v[j].w * v[j].w;
    #pragma unroll
    for (int off = 8; off; off >>= 1) s += __shfl_xor(s, off, 64);
    const float inv = 1.0f / sqrtf(s);
    __hip_bfloat16* wp = out + (size_t)row * DIM + li * 4;
    #pragma unroll
    for (int j = 0; j < 4; ++j) {
        __hip_bfloat16 o[4];
        o[0] = __float2bfloat16(v[j].x * inv);
        o[1] = __float2bfloat16(v[j].y * inv);
        o[2] = __float2bfloat16(v[j].z * inv);
        o[3] = __float2bfloat16(v[j].w * inv);
        *(uint2*)(wp + j * 64) = *(uint2*)o;
    }
}

// A-in-registers GEMM+top3 at the 104-VGPR working point (R5-proven), with
// the R0-proven 2-blocks/CU overlap restored.
// R8 POST-MORTEM: arch-VGPR cap is 128 at any multi-wave/EU occupancy (three
// attribute spellings all gave VGPR_Count=128); rt=4 (af=128 regs) cannot fit
// -> rt=2 (af[2][8]=64, total ~104, no spill). rt=2 is LDS-read-bound
// (reads/MFMA=0.5 -> floor ~41us), and R5 showed a SINGLE block/CU leaves
// ~37us of exposed latency on top (78us measured). Fix: 4-wave blocks,
// grid 512 = 2 independent blocks/CU covering each other's stalls.
// Block = 128 rows x 2048 cols; wave = 32 rows; TC=64 (ct=4), NT=32.
// B streams through LDS 32KB tiles, double-buffered (64KB/block; 128KB/CU for
// 2 blocks), staged 2 ahead, counted vmcnt(8) gates (never 0 until drain),
// 2 barriers/tile. cs = bid&7 == XCD (round-robin): both resident blocks of a
// CU read the same XCD-local 1MB B slab from L2.
// Swizzle: col c chunk g at phys g^(c&7), folded into the global source.
__global__ __launch_bounds__(256, 2) void gemm_top3_kernel(
        const __hip_bfloat16* __restrict__ A, const __hip_bfloat16* __restrict__ B,
        float* __restrict__ partial) {
    __shared__ char smem[2 * 32768];   // B tile double buffer

    const int tid  = threadIdx.x;
    const int wave = tid >> 6;
    const int lane = tid & 63;
    const int lo   = lane & 15;
    const int quad = lane >> 4;
    const int cs   = blockIdx.x & 7;   // round-robin dispatch -> cs == XCD
    const int rb   = blockIdx.x >> 3;
    const int row0 = rb * BM;

    // ---- A fragments in registers: af[rt][s] = A[row0+wave*32+rt*16+lo][s*32+quad*8 ..+7]
    v8s af[2][8];
    {
        const char* arow = (const char*)A + (size_t)(row0 + wave * 32 + lo) * 512 + quad * 16;
        #pragma unroll
        for (int rt = 0; rt < 2; ++rt)
            #pragma unroll
            for (int s = 0; s < 8; ++s)
                af[rt][s] = *(const v8s*)(arow + rt * 8192 + s * 64);
    }
    // af loads must complete before staging so in-loop vmcnt counts are pure B.
    asm volatile("s_waitcnt vmcnt(0)" ::: "memory");

    // ---- staging constants: 8 GLD16/thread/tile. For j=0..7:
    // col = j*8 + wave*2 + (lane>>5); phys chunk = lane&31;
    // source logical chunk = (lane&31)^(col&7). LDS dst = j*4096 + wave*1024
    // (+ lane*16 by HW) == col*512 + phys*16 exactly. ----
    const char* Bb = (const char*)B + (size_t)cs * COLS * 512;
    int gsrc[8];
    #pragma unroll
    for (int j = 0; j < 8; ++j) {
        const int col = j * 8 + wave * 2 + (lane >> 5);
        gsrc[j] = col * 512 + (((lane & 31) ^ (col & 7)) << 4);
    }

    // ---- read-side swizzle: phys = (s*4+quad) ^ (col&7); (ct*16+lo)&7 == lo&7 ----
    int swz[8];
    #pragma unroll
    for (int s = 0; s < 8; ++s) swz[s] = (((s * 4 + quad) ^ (lo & 7)) << 4);
    int bco[4];
    #pragma unroll
    for (int ct = 0; ct < 4; ++ct) bco[ct] = (ct * 16 + lo) * 512;

    float t0[8], t1[8], t2[8];
    #pragma unroll
    for (int i = 0; i < 8; ++i) { t0[i] = -1e30f; t1[i] = -1e30f; t2[i] = -1e30f; }

    // ---- prologue: stage tiles 0 and 1 ----
    #pragma unroll
    for (int j = 0; j < 8; ++j)
        GLD16(Bb + gsrc[j], smem + j * 4096 + wave * 1024);
    #pragma unroll
    for (int j = 0; j < 8; ++j)
        GLD16(Bb + 32768 + gsrc[j], smem + 32768 + j * 4096 + wave * 1024);

    #pragma unroll 2
    for (int t = 0; t < NT; ++t) {
        if (t == NT - 1) asm volatile("s_waitcnt vmcnt(0)" ::: "memory");
        else             asm volatile("s_waitcnt vmcnt(8)" ::: "memory");
        __builtin_amdgcn_s_barrier();    // all waves: tile t landed

        const char* bbuf = smem + (t & 1) * 32768;
        f32x4 acc[2][4];
        __builtin_amdgcn_s_setprio(1);
        #pragma unroll
        for (int s = 0; s < 8; ++s) {
            #pragma unroll
            for (int ct = 0; ct < 4; ++ct) {
                v8s bf = *(const v8s*)(bbuf + bco[ct] + swz[s]);
                #pragma unroll
                for (int rt = 0; rt < 2; ++rt) {
                    if (s == 0)
                        acc[rt][ct] = __builtin_amdgcn_mfma_f32_16x16x32_bf16(
                            af[rt][0], bf, (f32x4){0.f, 0.f, 0.f, 0.f}, 0, 0, 0);
                    else
                        acc[rt][ct] = __builtin_amdgcn_mfma_f32_16x16x32_bf16(
                            af[rt][s], bf, acc[rt][ct], 0, 0, 0);
                }
            }
        }
        __builtin_amdgcn_s_setprio(0);
        __builtin_amdgcn_s_barrier();    // all waves done reading buf[t&1]
        if (t + 2 < NT) {                // stage t+2 into the buffer just freed
            const char* src = Bb + (size_t)(t + 2) * 32768;
            char* dst = smem + (t & 1) * 32768;
            #pragma unroll
            for (int j = 0; j < 8; ++j)
                GLD16(src + gsrc[j], dst + j * 4096 + wave * 1024);
        }
        // fold this tile's 32 C-values/lane into running top3 (VALU; hides
        // under the in-flight stage)
        #pragma unroll
        for (int rt = 0; rt < 2; ++rt)
            #pragma unroll
            for (int r = 0; r < 4; ++r) {
                const int sl = rt * 4 + r;
                #pragma unroll
                for (int ct = 0; ct < 4; ++ct)
                    top3_insert(acc[rt][ct][r], t0[sl], t1[sl], t2[sl]);
            }
    }

    // merge across the 16 lo-lanes (same row, different col residues)
    #pragma unroll
    for (int sl = 0; sl < 8; ++sl) {
        #pragma unroll
        for (int step = 1; step < 16; step <<= 1) {
            float b0 = __shfl_xor(t0[sl], step, 64);
            float b1 = __shfl_xor(t1[sl], step, 64);
            float b2 = __shfl_xor(t2[sl], step, 64);
            top3_insert(b0, t0[sl], t1[sl], t2[sl]);
            top3_insert(b1, t0[sl], t1[sl], t2[sl]);
            top3_insert(b2, t0[sl], t1[sl], t2[sl]);
        }
    }
    if (lo == 0) {
        #pragma unroll
        for (int rt = 0; rt < 2; ++rt)
            #pragma unroll
            for (int r = 0; r < 4; ++r) {
                const int row = row0 + wave * 32 + rt * 16 + quad * 4 + r;
                float* p = partial + ((size_t)row * NPART + cs) * 3;
                const int sl = rt * 4 + r;
                p[0] = t0[sl]; p[1] = t1[sl]; p[2] = t2[sl];
            }
    }
}

// 1 thread per row: 6 float4 loads (24 values), 24 inserts.
__global__ __launch_bounds__(256) void merge_kernel(
        const float* __restrict__ partial, float* __restrict__ out) {
    const int row = blockIdx.x * 256 + threadIdx.x;
    if (row >= N1) return;
    const float4* p = (const float4*)(partial + (size_t)row * NPART * 3);
    float t0 = -1e30f, t1 = -1e30f, t2 = -1e30f;
    #pragma unroll
    for (int i = 0; i < 6; ++i) {
        float4 v = p[i];
        top3_insert(v.x, t0, t1, t2);
        top3_insert(v.y, t0, t1, t2);
        top3_insert(v.z, t0, t1, t2);
        top3_insert(v.w, t0, t1, t2);
    }
    out[row] = (t0 + t1 + t2) * (1.0f / 3.0f);
}

extern "C" void kernel_launch(void* const* d_in, const int* in_sizes, int n_in,
                              void* d_out, int out_size, void* d_ws, size_t ws_size,
                              hipStream_t stream) {
    const float* tA = (const float*)d_in[0];
    const float* tB = (const float*)d_in[1];
    float* out = (float*)d_out;

    __hip_bfloat16* An = (__hip_bfloat16*)d_ws;
    __hip_bfloat16* Bn = An + (size_t)N1 * DIM;
    float* partial = (float*)(Bn + (size_t)N2 * DIM);

    normalize_kernel<<<(N1 + N2) / 16, 256, 0, stream>>>(tA, tB, An, Bn);
    gemm_top3_kernel<<<(N1 / BM) * CS, 256, 0, stream>>>(An, Bn, partial);
    merge_kernel<<<N1 / 256, 256, 0, stream>>>(partial, out);
}

// Round 10
// 144.905 us; speedup vs baseline: 1.1749x; 1.0056x over previous
//
#include <hip/hip_runtime.h>
#include <hip/hip_bf16.h>
#include <stdint.h>

#define N1 8192
#define N2 16384
#define DIM 256
#define BM 128              // rows per block = 4 waves x 32
#define CS 8                // col-splits (== 8 XCDs)
#define COLS (N2 / CS)      // 2048 cols per block
#define TC 64               // cols per tile (ct=4)
#define NT (COLS / TC)      // 32 tiles per block
#define NPART CS

typedef short v8s  __attribute__((ext_vector_type(8)));   // 8 x bf16 bits
typedef float f32x4 __attribute__((ext_vector_type(4)));

#define GLD16(g, l)                                                                         \
  __builtin_amdgcn_global_load_lds((const __attribute__((address_space(1))) uint32_t*)(g),  \
                                   (__attribute__((address_space(3))) uint32_t*)(l), 16, 0, 0)

__device__ __forceinline__ void top3_insert(float v, float& t0, float& t1, float& t2) {
    float nt1 = __builtin_amdgcn_fmed3f(v, t0, t1);
    float nt2 = __builtin_amdgcn_fmed3f(v, t1, t2);
    t0 = fmaxf(t0, v);
    t1 = nt1;
    t2 = nt2;
}

// 16 lanes per row, 4 rows per wave, 16 rows per block. Each lane: 4 x float4
// loads in flight (ILP), 4-step width-16 shuffle reduce, 4 x uint2 stores.
__global__ __launch_bounds__(256) void normalize_kernel(
        const float* __restrict__ inA, const float* __restrict__ inB,
        __hip_bfloat16* __restrict__ outA, __hip_bfloat16* __restrict__ outB) {
    const int wave = threadIdx.x >> 6;
    const int lane = threadIdx.x & 63;
    const int rgrp = lane >> 4;
    const int li   = lane & 15;
    const int gr   = blockIdx.x * 16 + wave * 4 + rgrp;   // 0..24575
    const float* in;
    __hip_bfloat16* out;
    int row;
    if (gr < N1) { in = inA; out = outA; row = gr; }
    else         { in = inB; out = outB; row = gr - N1; }
    const float* rp = in + (size_t)row * DIM + li * 4;
    float4 v[4];
    #pragma unroll
    for (int j = 0; j < 4; ++j) v[j] = *(const float4*)(rp + j * 64);
    float s = 0.f;
    #pragma unroll
    for (int j = 0; j < 4; ++j)
        s += v[j].x * v[j].x + v[j].y * v[j].y + v[j].z * v[j].z + v[j].w * v[j].w;
    #pragma unroll
    for (int off = 8; off; off >>= 1) s += __shfl_xor(s, off, 64);
    const float inv = 1.0f / sqrtf(s);
    __hip_bfloat16* wp = out + (size_t)row * DIM + li * 4;
    #pragma unroll
    for (int j = 0; j < 4; ++j) {
        __hip_bfloat16 o[4];
        o[0] = __float2bfloat16(v[j].x * inv);
        o[1] = __float2bfloat16(v[j].y * inv);
        o[2] = __float2bfloat16(v[j].z * inv);
        o[3] = __float2bfloat16(v[j].w * inv);
        *(uint2*)(wp + j * 64) = *(uint2*)o;
    }
}

// A-in-registers GEMM+top3, rt=2, 4-wave blocks, 2 blocks/CU (R9 base).
// R9 POST-MORTEM: LDS-read pipe is the critical resource (131k of 194k cyc/CU)
// and every ds_read_b128 paid exactly +4 conflict cycles (8.4M = 4 x 2^21
// reads). R0 measured ZERO conflicts with identical swizzle math but
// COMPILE-TIME-CONSTANT LDS bases; R5/R9 use a runtime (t&1)*32768 base.
// THIS ROUND'S SINGLE CHANGE: explicit two-tile loop body so every LDS read
// and stage destination has a static base (buf0 @0 / buf1 @32768), restoring
// the R0 addressing pattern. Gates/swizzle/staging/fold unchanged from R9.
// Structure: block = 128 rows x 2048 cols; wave = 32 rows; TC=64 (ct=4),
// NT=32 tiles; B tiles 32KB double-buffered (64KB/block, 128KB/CU), staged
// 2 ahead, counted vmcnt(8) gates (never 0 until drain), 2 barriers/tile.
// cs = bid&7 == XCD: both resident blocks of a CU read the same XCD-local
// 1MB B slab from L2. Swizzle: col c chunk g at phys g^(c&7), folded into
// the global-side source address.
__global__ __launch_bounds__(256, 2) void gemm_top3_kernel(
        const __hip_bfloat16* __restrict__ A, const __hip_bfloat16* __restrict__ B,
        float* __restrict__ partial) {
    __shared__ char smem[2 * 32768];   // B tile double buffer (static bases)

    const int tid  = threadIdx.x;
    const int wave = tid >> 6;
    const int lane = tid & 63;
    const int lo   = lane & 15;
    const int quad = lane >> 4;
    const int cs   = blockIdx.x & 7;   // round-robin dispatch -> cs == XCD
    const int rb   = blockIdx.x >> 3;
    const int row0 = rb * BM;

    // ---- A fragments in registers: af[rt][s] = A[row0+wave*32+rt*16+lo][s*32+quad*8 ..+7]
    v8s af[2][8];
    {
        const char* arow = (const char*)A + (size_t)(row0 + wave * 32 + lo) * 512 + quad * 16;
        #pragma unroll
        for (int rt = 0; rt < 2; ++rt)
            #pragma unroll
            for (int s = 0; s < 8; ++s)
                af[rt][s] = *(const v8s*)(arow + rt * 8192 + s * 64);
    }
    // af loads must complete before staging so in-loop vmcnt counts are pure B.
    asm volatile("s_waitcnt vmcnt(0)" ::: "memory");

    // ---- staging constants: 8 GLD16/thread/tile. For j=0..7:
    // col = j*8 + wave*2 + (lane>>5); phys chunk = lane&31;
    // source logical chunk = (lane&31)^(col&7). LDS dst = j*4096 + wave*1024
    // (+ lane*16 by HW) == col*512 + phys*16 exactly. ----
    const char* Bb = (const char*)B + (size_t)cs * COLS * 512;
    int gsrc[8];
    #pragma unroll
    for (int j = 0; j < 8; ++j) {
        const int col = j * 8 + wave * 2 + (lane >> 5);
        gsrc[j] = col * 512 + (((lane & 31) ^ (col & 7)) << 4);
    }

    // ---- read-side swizzle: phys = (s*4+quad) ^ (col&7); (ct*16+lo)&7 == lo&7 ----
    int swz[8];
    #pragma unroll
    for (int s = 0; s < 8; ++s) swz[s] = (((s * 4 + quad) ^ (lo & 7)) << 4);
    int bco[4];
    #pragma unroll
    for (int ct = 0; ct < 4; ++ct) bco[ct] = (ct * 16 + lo) * 512;

    float t0[8], t1[8], t2[8];
    #pragma unroll
    for (int i = 0; i < 8; ++i) { t0[i] = -1e30f; t1[i] = -1e30f; t2[i] = -1e30f; }

    // ---- prologue: stage tiles 0 (buf0) and 1 (buf1) ----
    #pragma unroll
    for (int j = 0; j < 8; ++j)
        GLD16(Bb + gsrc[j], smem + j * 4096 + wave * 1024);
    #pragma unroll
    for (int j = 0; j < 8; ++j)
        GLD16(Bb + 32768 + gsrc[j], smem + 32768 + j * 4096 + wave * 1024);

    // macro: one tile with STATIC buffer base BOFF; stages tile (tt2) into the
    // same buffer afterwards when stage_ok.
    #define DO_TILE(BOFF, GATE8, stage_ok, src_off)                                        \
    {                                                                                      \
        if (GATE8) asm volatile("s_waitcnt vmcnt(8)" ::: "memory");                        \
        else       asm volatile("s_waitcnt vmcnt(0)" ::: "memory");                        \
        __builtin_amdgcn_s_barrier();                                                      \
        f32x4 acc[2][4];                                                                   \
        __builtin_amdgcn_s_setprio(1);                                                     \
        _Pragma("unroll")                                                                  \
        for (int s = 0; s < 8; ++s) {                                                      \
            _Pragma("unroll")                                                              \
            for (int ct = 0; ct < 4; ++ct) {                                               \
                v8s bf = *(const v8s*)(smem + (BOFF) + bco[ct] + swz[s]);                  \
                _Pragma("unroll")                                                          \
                for (int rt = 0; rt < 2; ++rt) {                                           \
                    if (s == 0)                                                            \
                        acc[rt][ct] = __builtin_amdgcn_mfma_f32_16x16x32_bf16(             \
                            af[rt][0], bf, (f32x4){0.f, 0.f, 0.f, 0.f}, 0, 0, 0);          \
                    else                                                                   \
                        acc[rt][ct] = __builtin_amdgcn_mfma_f32_16x16x32_bf16(             \
                            af[rt][s], bf, acc[rt][ct], 0, 0, 0);                          \
                }                                                                          \
            }                                                                              \
        }                                                                                  \
        __builtin_amdgcn_s_setprio(0);                                                     \
        __builtin_amdgcn_s_barrier();                                                      \
        if (stage_ok) {                                                                    \
            const char* src = Bb + (size_t)(src_off);                                      \
            _Pragma("unroll")                                                              \
            for (int j = 0; j < 8; ++j)                                                    \
                GLD16(src + gsrc[j], smem + (BOFF) + j * 4096 + wave * 1024);              \
        }                                                                                  \
        _Pragma("unroll")                                                                  \
        for (int rt = 0; rt < 2; ++rt)                                                     \
            _Pragma("unroll")                                                              \
            for (int r = 0; r < 4; ++r) {                                                  \
                const int sl = rt * 4 + r;                                                 \
                _Pragma("unroll")                                                          \
                for (int ct = 0; ct < 4; ++ct)                                             \
                    top3_insert(acc[rt][ct][r], t0[sl], t1[sl], t2[sl]);                   \
            }                                                                              \
    }

    for (int tt = 0; tt < NT / 2; ++tt) {
        const int te = 2 * tt;                 // even tile -> buf0
        const bool st = (tt < NT / 2 - 1);
        // tile te (buf0): t+1's 8 loads stay in flight -> vmcnt(8)
        DO_TILE(0,     true, st, (size_t)(te + 2) * 32768);
        // tile te+1 (buf1): if staged above, 8 outstanding -> vmcnt(8); at the
        // last pair nothing was staged -> drain to 0.
        DO_TILE(32768, st,   st, (size_t)(te + 3) * 32768);
    }
    #undef DO_TILE

    // merge across the 16 lo-lanes (same row, different col residues)
    #pragma unroll
    for (int sl = 0; sl < 8; ++sl) {
        #pragma unroll
        for (int step = 1; step < 16; step <<= 1) {
            float b0 = __shfl_xor(t0[sl], step, 64);
            float b1 = __shfl_xor(t1[sl], step, 64);
            float b2 = __shfl_xor(t2[sl], step, 64);
            top3_insert(b0, t0[sl], t1[sl], t2[sl]);
            top3_insert(b1, t0[sl], t1[sl], t2[sl]);
            top3_insert(b2, t0[sl], t1[sl], t2[sl]);
        }
    }
    if (lo == 0) {
        #pragma unroll
        for (int rt = 0; rt < 2; ++rt)
            #pragma unroll
            for (int r = 0; r < 4; ++r) {
                const int row = row0 + wave * 32 + rt * 16 + quad * 4 + r;
                float* p = partial + ((size_t)row * NPART + cs) * 3;
                const int sl = rt * 4 + r;
                p[0] = t0[sl]; p[1] = t1[sl]; p[2] = t2[sl];
            }
    }
}

// 1 thread per row: 6 float4 loads (24 values), 24 inserts.
__global__ __launch_bounds__(256) void merge_kernel(
        const float* __restrict__ partial, float* __restrict__ out) {
    const int row = blockIdx.x * 256 + threadIdx.x;
    if (row >= N1) return;
    const float4* p = (const float4*)(partial + (size_t)row * NPART * 3);
    float t0 = -1e30f, t1 = -1e30f, t2 = -1e30f;
    #pragma unroll
    for (int i = 0; i < 6; ++i) {
        float4 v = p[i];
        top3_insert(v.x, t0, t1, t2);
        top3_insert(v.y, t0, t1, t2);
        top3_insert(v.z, t0, t1, t2);
        top3_insert(v.w, t0, t1, t2);
    }
    out[row] = (t0 + t1 + t2) * (1.0f / 3.0f);
}

extern "C" void kernel_launch(void* const* d_in, const int* in_sizes, int n_in,
                              void* d_out, int out_size, void* d_ws, size_t ws_size,
                              hipStream_t stream) {
    const float* tA = (const float*)d_in[0];
    const float* tB = (const float*)d_in[1];
    float* out = (float*)d_out;

    __hip_bfloat16* An = (__hip_bfloat16*)d_ws;
    __hip_bfloat16* Bn = An + (size_t)N1 * DIM;
    float* partial = (float*)(Bn + (size_t)N2 * DIM);

    normalize_kernel<<<(N1 + N2) / 16, 256, 0, stream>>>(tA, tB, An, Bn);
    gemm_top3_kernel<<<(N1 / BM) * CS, 256, 0, stream>>>(An, Bn, partial);
    merge_kernel<<<N1 / 256, 256, 0, stream>>>(partial, out);
}

// Round 11
// 138.231 us; speedup vs baseline: 1.2316x; 1.0483x over previous
//
#include <hip/hip_runtime.h>
#include <hip/hip_bf16.h>
#include <stdint.h>

#define N1 8192
#define N2 16384
#define DIM 256
#define BM 256              // rows per block = 4 waves x 64
#define CS 16               // col-splits
#define COLS (N2 / CS)      // 1024 cols per block
#define TC 32               // cols per tile (ct=2)
#define NT (COLS / TC)      // 32 tiles per block
#define NPART CS

typedef short v8s  __attribute__((ext_vector_type(8)));   // 8 x bf16 bits
typedef float f32x4 __attribute__((ext_vector_type(4)));

#define GLD16(g, l)                                                                         \
  __builtin_amdgcn_global_load_lds((const __attribute__((address_space(1))) uint32_t*)(g),  \
                                   (__attribute__((address_space(3))) uint32_t*)(l), 16, 0, 0)

__device__ __forceinline__ void top3_insert(float v, float& t0, float& t1, float& t2) {
    float nt1 = __builtin_amdgcn_fmed3f(v, t0, t1);
    float nt2 = __builtin_amdgcn_fmed3f(v, t1, t2);
    t0 = fmaxf(t0, v);
    t1 = nt1;
    t2 = nt2;
}

// 16 lanes per row, 4 rows per wave, 16 rows per block. Each lane: 4 x float4
// loads in flight (ILP), 4-step width-16 shuffle reduce, 4 x uint2 stores.
__global__ __launch_bounds__(256) void normalize_kernel(
        const float* __restrict__ inA, const float* __restrict__ inB,
        __hip_bfloat16* __restrict__ outA, __hip_bfloat16* __restrict__ outB) {
    const int wave = threadIdx.x >> 6;
    const int lane = threadIdx.x & 63;
    const int rgrp = lane >> 4;
    const int li   = lane & 15;
    const int gr   = blockIdx.x * 16 + wave * 4 + rgrp;   // 0..24575
    const float* in;
    __hip_bfloat16* out;
    int row;
    if (gr < N1) { in = inA; out = outA; row = gr; }
    else         { in = inB; out = outB; row = gr - N1; }
    const float* rp = in + (size_t)row * DIM + li * 4;
    float4 v[4];
    #pragma unroll
    for (int j = 0; j < 4; ++j) v[j] = *(const float4*)(rp + j * 64);
    float s = 0.f;
    #pragma unroll
    for (int j = 0; j < 4; ++j)
        s += v[j].x * v[j].x + v[j].y * v[j].y + v[j].z * v[j].z + v[j].w * v[j].w;
    #pragma unroll
    for (int off = 8; off; off >>= 1) s += __shfl_xor(s, off, 64);
    const float inv = 1.0f / sqrtf(s);
    __hip_bfloat16* wp = out + (size_t)row * DIM + li * 4;
    #pragma unroll
    for (int j = 0; j < 4; ++j) {
        __hip_bfloat16 o[4];
        o[0] = __float2bfloat16(v[j].x * inv);
        o[1] = __float2bfloat16(v[j].y * inv);
        o[2] = __float2bfloat16(v[j].z * inv);
        o[3] = __float2bfloat16(v[j].w * inv);
        *(uint2*)(wp + j * 64) = *(uint2*)o;
    }
}

// A-in-AGPR GEMM+top3, rt=4. Block = 4 waves x 64 rows = 256 rows x 1024 cols.
// R10 POST-MORTEM: reads/MFMA = 1/rt is the ceiling (LDS pipe 131k cyc/CU >
// MFMA 79.5k at rt=2), and rt=4 needs 128 regs for af — over the 128-arch-VGPR
// wall the compiler enforces (R6-R8 spilled to SCRATCH, never to AGPRs).
// FIX: pin af into AGPRs explicitly (empty-asm "=a"/"0" tie) and issue MFMA
// via inline asm with the A-operand in "a" — gfx950 MFMA reads A directly
// from AGPRs (ISA §10). Budget: 128 AGPR af + ~115 arch VGPR = ~243/wave ->
// 2 waves/SIMD. rt=4 halves LDS reads: ~25k cyc reads + ~8k conflicts + 8k
// writes vs 79.5k MFMA -> MFMA-bound, 2x LDS headroom.
// B streams through LDS: 16KB tiles (TC=32), double-buffered (32KB/block,
// 64KB/CU), staged 2 ahead, counted vmcnt(4) gates (never 0 until drain),
// 2 barriers/tile, static buffer bases (R10 macro). grid 512 = 2 blocks/CU.
// Swizzle: col c chunk g at phys g^(c&7), folded into the global source.
__global__ __launch_bounds__(256, 2) void gemm_top3_kernel(
        const __hip_bfloat16* __restrict__ A, const __hip_bfloat16* __restrict__ B,
        float* __restrict__ partial) {
    __shared__ char smem[2 * 16384];   // B tile double buffer (static bases)

    const int tid  = threadIdx.x;
    const int wave = tid >> 6;
    const int lane = tid & 63;
    const int lo   = lane & 15;
    const int quad = lane >> 4;
    const int cs   = blockIdx.x & 15;
    const int rb   = blockIdx.x >> 4;
    const int row0 = rb * BM;

    // ---- A fragments pinned in AGPRs:
    // af[rt][s] = A[row0+wave*64+rt*16+lo][s*32+quad*8 .. +7]
    v8s af[4][8];
    {
        const char* arow = (const char*)A + (size_t)(row0 + wave * 64 + lo) * 512 + quad * 16;
        #pragma unroll
        for (int rt = 0; rt < 4; ++rt)
            #pragma unroll
            for (int s = 0; s < 8; ++s) {
                v8s t = *(const v8s*)(arow + rt * 8192 + s * 64);
                asm("" : "=a"(af[rt][s]) : "0"(t));   // pin: lives in AGPRs
            }
    }
    // af loads complete before staging so in-loop vmcnt counts are pure B.
    asm volatile("s_waitcnt vmcnt(0)" ::: "memory");

    // ---- staging constants: 4 GLD16/thread/tile. For j=0..3:
    // col = j*8 + wave*2 + (lane>>5); phys chunk = lane&31;
    // source logical chunk = (lane&31)^(col&7). LDS dst = j*4096 + wave*1024
    // (+ lane*16 by HW) == col*512 + phys*16 exactly. ----
    const char* Bb = (const char*)B + (size_t)cs * COLS * 512;
    int gsrc[4];
    #pragma unroll
    for (int j = 0; j < 4; ++j) {
        const int col = j * 8 + wave * 2 + (lane >> 5);
        gsrc[j] = col * 512 + (((lane & 31) ^ (col & 7)) << 4);
    }

    // ---- read-side swizzle: phys = (s*4+quad) ^ (col&7); (16+lo)&7 == lo&7 ----
    int swz[8];
    #pragma unroll
    for (int s = 0; s < 8; ++s) swz[s] = (((s * 4 + quad) ^ (lo & 7)) << 4);
    const int bco0 = lo * 512;            // ct=0: col lo
    const int bco1 = (16 + lo) * 512;     // ct=1: col 16+lo

    float t0[16], t1[16], t2[16];
    #pragma unroll
    for (int i = 0; i < 16; ++i) { t0[i] = -1e30f; t1[i] = -1e30f; t2[i] = -1e30f; }

    // ---- prologue: stage tiles 0 (buf0) and 1 (buf1) ----
    #pragma unroll
    for (int j = 0; j < 4; ++j)
        GLD16(Bb + gsrc[j], smem + j * 4096 + wave * 1024);
    #pragma unroll
    for (int j = 0; j < 4; ++j)
        GLD16(Bb + 16384 + gsrc[j], smem + 16384 + j * 4096 + wave * 1024);

    // one tile with STATIC buffer base BOFF; stages a later tile into the same
    // buffer afterwards when stage_ok. MFMA: A from AGPR ("a"), B from VGPR.
    #define DO_TILE(BOFF, GATE4, stage_ok, src_off)                                        \
    {                                                                                      \
        if (GATE4) asm volatile("s_waitcnt vmcnt(4)" ::: "memory");                        \
        else       asm volatile("s_waitcnt vmcnt(0)" ::: "memory");                        \
        __builtin_amdgcn_s_barrier();                                                      \
        f32x4 acc[4][2];                                                                   \
        _Pragma("unroll")                                                                  \
        for (int rt = 0; rt < 4; ++rt) {                                                   \
            acc[rt][0] = (f32x4){0.f, 0.f, 0.f, 0.f};                                      \
            acc[rt][1] = (f32x4){0.f, 0.f, 0.f, 0.f};                                      \
        }                                                                                  \
        __builtin_amdgcn_s_setprio(1);                                                     \
        _Pragma("unroll")                                                                  \
        for (int s = 0; s < 8; ++s) {                                                      \
            v8s bf0 = *(const v8s*)(smem + (BOFF) + bco0 + swz[s]);                        \
            v8s bf1 = *(const v8s*)(smem + (BOFF) + bco1 + swz[s]);                        \
            _Pragma("unroll")                                                              \
            for (int rt = 0; rt < 4; ++rt) {                                               \
                asm("v_mfma_f32_16x16x32_bf16 %0, %1, %2, %0"                              \
                    : "+v"(acc[rt][0]) : "a"(af[rt][s]), "v"(bf0));                        \
                asm("v_mfma_f32_16x16x32_bf16 %0, %1, %2, %0"                              \
                    : "+v"(acc[rt][1]) : "a"(af[rt][s]), "v"(bf1));                        \
            }                                                                              \
        }                                                                                  \
        __builtin_amdgcn_s_setprio(0);                                                     \
        __builtin_amdgcn_s_barrier();                                                      \
        if (stage_ok) {                                                                    \
            const char* src = Bb + (size_t)(src_off);                                      \
            _Pragma("unroll")                                                              \
            for (int j = 0; j < 4; ++j)                                                    \
                GLD16(src + gsrc[j], smem + (BOFF) + j * 4096 + wave * 1024);              \
        }                                                                                  \
        _Pragma("unroll")                                                                  \
        for (int rt = 0; rt < 4; ++rt)                                                     \
            _Pragma("unroll")                                                              \
            for (int r = 0; r < 4; ++r) {                                                  \
                const int sl = rt * 4 + r;                                                 \
                top3_insert(acc[rt][0][r], t0[sl], t1[sl], t2[sl]);                        \
                top3_insert(acc[rt][1][r], t0[sl], t1[sl], t2[sl]);                        \
            }                                                                              \
    }

    for (int tt = 0; tt < NT / 2; ++tt) {
        const int te = 2 * tt;                 // even tile -> buf0
        const bool st = (tt < NT / 2 - 1);
        // tile te (buf0): te+1's 4 loads stay in flight -> vmcnt(4)
        DO_TILE(0,     true, st, (size_t)(te + 2) * 16384);
        // tile te+1 (buf1): if staged above, 4 outstanding -> vmcnt(4); at the
        // last pair nothing was staged -> drain to 0.
        DO_TILE(16384, st,   st, (size_t)(te + 3) * 16384);
    }
    #undef DO_TILE

    // merge across the 16 lo-lanes (same row, different col residues)
    #pragma unroll
    for (int sl = 0; sl < 16; ++sl) {
        #pragma unroll
        for (int step = 1; step < 16; step <<= 1) {
            float b0 = __shfl_xor(t0[sl], step, 64);
            float b1 = __shfl_xor(t1[sl], step, 64);
            float b2 = __shfl_xor(t2[sl], step, 64);
            top3_insert(b0, t0[sl], t1[sl], t2[sl]);
            top3_insert(b1, t0[sl], t1[sl], t2[sl]);
            top3_insert(b2, t0[sl], t1[sl], t2[sl]);
        }
    }
    if (lo == 0) {
        #pragma unroll
        for (int rt = 0; rt < 4; ++rt)
            #pragma unroll
            for (int r = 0; r < 4; ++r) {
                const int row = row0 + wave * 64 + rt * 16 + quad * 4 + r;
                float* p = partial + ((size_t)row * NPART + cs) * 3;
                const int sl = rt * 4 + r;
                p[0] = t0[sl]; p[1] = t1[sl]; p[2] = t2[sl];
            }
    }
}

// 1 thread per row: 12 float4 loads (48 values), 48 inserts.
__global__ __launch_bounds__(256) void merge_kernel(
        const float* __restrict__ partial, float* __restrict__ out) {
    const int row = blockIdx.x * 256 + threadIdx.x;
    if (row >= N1) return;
    const float4* p = (const float4*)(partial + (size_t)row * NPART * 3);
    float t0 = -1e30f, t1 = -1e30f, t2 = -1e30f;
    #pragma unroll
    for (int i = 0; i < 12; ++i) {
        float4 v = p[i];
        top3_insert(v.x, t0, t1, t2);
        top3_insert(v.y, t0, t1, t2);
        top3_insert(v.z, t0, t1, t2);
        top3_insert(v.w, t0, t1, t2);
    }
    out[row] = (t0 + t1 + t2) * (1.0f / 3.0f);
}

extern "C" void kernel_launch(void* const* d_in, const int* in_sizes, int n_in,
                              void* d_out, int out_size, void* d_ws, size_t ws_size,
                              hipStream_t stream) {
    const float* tA = (const float*)d_in[0];
    const float* tB = (const float*)d_in[1];
    float* out = (float*)d_out;

    __hip_bfloat16* An = (__hip_bfloat16*)d_ws;
    __hip_bfloat16* Bn = An + (size_t)N1 * DIM;
    float* partial = (float*)(Bn + (size_t)N2 * DIM);

    normalize_kernel<<<(N1 + N2) / 16, 256, 0, stream>>>(tA, tB, An, Bn);
    gemm_top3_kernel<<<(N1 / BM) * CS, 256, 0, stream>>>(An, Bn, partial);
    merge_kernel<<<N1 / 256, 256, 0, stream>>>(partial, out);
}